// Round 6
// baseline (318.675 us; speedup 1.0000x reference)
//
#include <hip/hip_runtime.h>
#include <hip/hip_bf16.h>

// ---------------------------------------------------------------------------
// GCN 2-layer forward on MI355X.
// Round 16: (1) spmm2 reverted to R14 structure (R15's uint2 rewrite
// regressed it 48->57.6us: VGPR 16->56, occ 36%, 3-round v2f shuffle tail);
// spmm1 keeps R15's uint2 form (improved). (2) Build collapsed 4->2 kernels:
// buildC = LDS dst-histogram + global-cursor partition reservation + scatter
// (CAP-padded buckets) + deg_out via direct global atomics + gcnt; passD2 =
// in-block scan of partition totals -> tight CSR + histogram/scan/scatter.
// norm_src array gone (rsqrt(deg) inline in gemm1/spmm1). 6 kernels total.
// R12-R14 retained: fp8 h1 (128B rows) + fp8 h2 (64B rows), fused pool,
// fp8 gemm epilogues with absorbed permutations.
// ---------------------------------------------------------------------------

#define NPP_SHIFT 9
#define NPP 512
#define MAXP 256
#define NB 512
#define CAPP 10240  // per-partition bucket capacity (mean 8192, sigma~90)

typedef __attribute__((ext_vector_type(8))) short frag8;
typedef __attribute__((ext_vector_type(4))) float f32x4;
typedef __attribute__((ext_vector_type(2))) float v2f;

// ---- buildC: one-pass graph build -------------------------------------
// Per block: LDS histogram of dst partition -> global cursor reservation ->
// scatter (d,s) into partition bucket. deg_out via global atomics. gcnt via
// LDS histogram + merge.
__launch_bounds__(256)
__global__ void buildC(const int* __restrict__ src, const int* __restrict__ dst,
                       int E, int P, int* __restrict__ cur,
                       int2* __restrict__ ebuf_dst, int* __restrict__ deg,
                       const int* __restrict__ gids, int N, int G,
                       int* __restrict__ gcnt) {
    __shared__ int h[MAXP], bs[MAXP], hg[MAXP];
    int tid = threadIdx.x;
    for (int i = tid; i < MAXP; i += 256) { h[i] = 0; hg[i] = 0; }
    __syncthreads();
    int per_block = (E + NB - 1) / NB;
    int e0 = blockIdx.x * per_block;
    int e1 = min(e0 + per_block, E);
    for (int e = e0 + tid; e < e1; e += 256) {
        atomicAdd(&h[dst[e] >> NPP_SHIFT], 1);
        atomicAdd(&deg[src[e]], 1);
    }
    int npb = (N + NB - 1) / NB;
    int n0 = blockIdx.x * npb;
    int n1 = min(n0 + npb, N);
    for (int i = n0 + tid; i < n1; i += 256) atomicAdd(&hg[gids[i]], 1);
    __syncthreads();
    for (int p = tid; p < P; p += 256) {
        int c = h[p];
        bs[p] = c ? atomicAdd(&cur[p], c) : 0;
        h[p] = 0;
    }
    for (int i = tid; i < G; i += 256)
        if (hg[i]) atomicAdd(&gcnt[i], hg[i]);
    __syncthreads();
    for (int e = e0 + tid; e < e1; e += 256) {
        int d = dst[e];
        int s = src[e];
        int p = d >> NPP_SHIFT;
        int lp = atomicAdd(&h[p], 1);
        ebuf_dst[(size_t)p * CAPP + bs[p] + lp] = make_int2(d, s);
    }
}

// ---- passD2: per-partition row_start + csr build (tight global offsets) -
__launch_bounds__(512)
__global__ void passD2(const int2* __restrict__ ebuf_dst, const int* __restrict__ cur,
                       int* __restrict__ row_start, int* __restrict__ csr_src,
                       int N, int E, int P) {
    __shared__ int hd[NPP], sc[NPP];
    int tid = threadIdx.x;
    int p = blockIdx.x;
    // global base for this partition = prefix sum of cur[0..p)
    sc[tid] = (tid < P) ? cur[tid] : 0;
    __syncthreads();
    for (int off = 1; off < 512; off <<= 1) {
        int t = (tid >= off) ? sc[tid - off] : 0;
        __syncthreads();
        sc[tid] += t;
        __syncthreads();
    }
    int gbase = (p > 0) ? sc[p - 1] : 0;
    __syncthreads();
    int node_lo = p << NPP_SHIFT;
    int nl = min(NPP, N - node_lo);
    hd[tid] = 0;
    __syncthreads();
    int ndst = cur[p];
    size_t base_d = (size_t)p * CAPP;
    for (int i = tid; i < ndst; i += 512)
        atomicAdd(&hd[ebuf_dst[base_d + i].x - node_lo], 1);
    __syncthreads();
    int myh = hd[tid];
    sc[tid] = myh;
    __syncthreads();
    for (int off = 1; off < 512; off <<= 1) {
        int t = (tid >= off) ? sc[tid - off] : 0;
        __syncthreads();
        sc[tid] += t;
        __syncthreads();
    }
    int row0 = gbase + sc[tid] - myh;
    if (tid < nl) row_start[node_lo + tid] = row0;
    if (p == P - 1 && tid == 0) row_start[N] = E;
    __syncthreads();
    hd[tid] = row0;  // reuse as cursor
    __syncthreads();
    for (int i = tid; i < ndst; i += 512) {
        int2 r = ebuf_dst[base_d + i];
        int pos = atomicAdd(&hd[r.x - node_lo], 1);
        csr_src[pos] = r.y;
    }
}

// ---- MFMA GEMM: out[n x COLS] = A[n x 128] @ W[128 x COLS] --------------
// FP8OUT, COLS==128: u32 slot s, byte c <-> feature 64*(s&1) + 16*c + (s>>1)
// FP8OUT, COLS==64:  u32 slot s, byte c <-> feature 16*c + s
// PERM: LDS W row k sources w[feat(k)] to absorb the permuted A layout.
template <int COLS, bool BF16IN, bool PERM, bool FP8OUT>
__launch_bounds__(256)
__global__ void gemm_mfma(const void* __restrict__ xin, const float* __restrict__ w,
                          const int* __restrict__ deg,
                          void* __restrict__ out, int n) {
    constexpr int NT = COLS / 16;
    __shared__ short wlds[4 * NT * 64 * 8];
    const int tid = threadIdx.x;
    for (int i = tid; i < 128 * COLS / 4; i += 256) {
        int k = (i * 4) / COLS;
        int n0 = (i * 4) % COLS;
        float4 wv;
        if constexpr (PERM) {
            int ksrc = 64 * ((k >> 2) & 1) + 16 * (k & 3) + (k >> 3);
            wv = *reinterpret_cast<const float4*>(w + (size_t)ksrc * COLS + n0);
        } else {
            wv = reinterpret_cast<const float4*>(w)[i];
        }
        int c = k >> 5, q = (k >> 3) & 3, j = k & 7;
        float vals[4] = {wv.x, wv.y, wv.z, wv.w};
#pragma unroll
        for (int u = 0; u < 4; ++u) {
            int nn = n0 + u;
            int t = nn >> 4;
            int ln = (q << 4) | (nn & 15);
            union { __hip_bfloat16 b; short s; } cv;
            cv.b = __float2bfloat16(vals[u]);
            wlds[(((c * NT + t) << 6) | ln) * 8 + j] = cv.s;
        }
    }
    __syncthreads();

    const int lane = tid & 63;
    const int wid = tid >> 6;
    const int m = lane & 15;
    const int q = lane >> 4;
    const int ntiles = (n + 15) >> 4;
    const frag8* wfr = reinterpret_cast<const frag8*>(wlds);

    for (int wt = blockIdx.x * 4 + wid; wt < ntiles; wt += gridDim.x * 4) {
        const int row = (wt << 4) + m;
        frag8 af[4];
        if (row < n) {
            if constexpr (BF16IN) {
                const frag8* xp = reinterpret_cast<const frag8*>(
                    (const __hip_bfloat16*)xin + (size_t)row * 128);
#pragma unroll
                for (int c = 0; c < 4; ++c) af[c] = xp[c * 4 + q];
            } else {
                const float* xp = (const float*)xin + (size_t)row * 128;
                float nm = rsqrtf((float)max(deg[row], 1));
#pragma unroll
                for (int c = 0; c < 4; ++c) {
                    int base = c * 32 + q * 8;
                    float4 v0 = *reinterpret_cast<const float4*>(xp + base);
                    float4 v1 = *reinterpret_cast<const float4*>(xp + base + 4);
                    union { frag8 f; short s[8]; } a;
                    union { __hip_bfloat16 b; short s; } cv;
                    cv.b = __float2bfloat16(v0.x * nm); a.s[0] = cv.s;
                    cv.b = __float2bfloat16(v0.y * nm); a.s[1] = cv.s;
                    cv.b = __float2bfloat16(v0.z * nm); a.s[2] = cv.s;
                    cv.b = __float2bfloat16(v0.w * nm); a.s[3] = cv.s;
                    cv.b = __float2bfloat16(v1.x * nm); a.s[4] = cv.s;
                    cv.b = __float2bfloat16(v1.y * nm); a.s[5] = cv.s;
                    cv.b = __float2bfloat16(v1.z * nm); a.s[6] = cv.s;
                    cv.b = __float2bfloat16(v1.w * nm); a.s[7] = cv.s;
                    af[c] = a.f;
                }
            }
        } else {
#pragma unroll
            for (int c = 0; c < 4; ++c) af[c] = frag8{0, 0, 0, 0, 0, 0, 0, 0};
        }
        f32x4 acc[NT] = {};
#pragma unroll
        for (int c = 0; c < 4; ++c)
#pragma unroll
            for (int t = 0; t < NT; ++t)
                acc[t] = __builtin_amdgcn_mfma_f32_16x16x32_bf16(
                    af[c], wfr[(c * NT + t) * 64 + lane], acc[t], 0, 0, 0);
#pragma unroll
        for (int r = 0; r < 4; ++r) {
            int grow = (wt << 4) + q * 4 + r;
            if (grow < n) {
                if constexpr (FP8OUT && COLS == 128) {
                    uint w0 = 0, w1 = 0;
                    w0 = (uint)__builtin_amdgcn_cvt_pk_fp8_f32(acc[0][r], acc[1][r], (int)w0, false);
                    w0 = (uint)__builtin_amdgcn_cvt_pk_fp8_f32(acc[2][r], acc[3][r], (int)w0, true);
                    w1 = (uint)__builtin_amdgcn_cvt_pk_fp8_f32(acc[4][r], acc[5][r], (int)w1, false);
                    w1 = (uint)__builtin_amdgcn_cvt_pk_fp8_f32(acc[6][r], acc[7][r], (int)w1, true);
                    reinterpret_cast<uint2*>(out)[(size_t)grow * 16 + m] = make_uint2(w0, w1);
                } else if constexpr (FP8OUT) {
                    uint w0 = 0;
                    w0 = (uint)__builtin_amdgcn_cvt_pk_fp8_f32(acc[0][r], acc[1][r], (int)w0, false);
                    w0 = (uint)__builtin_amdgcn_cvt_pk_fp8_f32(acc[2][r], acc[3][r], (int)w0, true);
                    reinterpret_cast<uint*>(out)[(size_t)grow * 16 + m] = w0;
                } else {
                    __hip_bfloat16* ob = reinterpret_cast<__hip_bfloat16*>(out);
#pragma unroll
                    for (int t = 0; t < NT; ++t)
                        ob[(size_t)grow * COLS + t * 16 + m] = __float2bfloat16(acc[t][r]);
                }
            }
        }
    }
}

// ---- SpMM layer 1: 2 dst rows/wave, uint2 gathers (4 edges/instr) -------
// h1 row = 16 uint2 (128B). lane: a=lane>>4 edge sub-idx, s=lane&15 slot.
__launch_bounds__(256)
__global__ void spmm1_kernel(const uint2* __restrict__ h1,
                             const int* __restrict__ row_start,
                             const int* __restrict__ csr_src,
                             const float* __restrict__ b1,
                             const int* __restrict__ deg,
                             uint4* __restrict__ x2n, int n) {
    int wv = (blockIdx.x * blockDim.x + threadIdx.x) >> 6;
    int lane = threadIdx.x & 63;
    int r0 = wv * 2;
    if (r0 >= n) return;
    int a = lane >> 4;
    int s = lane & 15;
    int e0[2], e1[2];
#pragma unroll
    for (int r = 0; r < 2; ++r) {
        int rr = min(r0 + r, n - 1);
        e0[r] = row_start[rr];
        e1[r] = row_start[rr + 1];
        if (r0 + r >= n) e1[r] = e0[r];
    }
    v2f acc[2][4] = {};
    int nb = max((e1[0] - e0[0] + 15) >> 4, (e1[1] - e0[1] + 15) >> 4);
    for (int b = 0; b < nb; ++b) {
        uint2 v[2][4];
#pragma unroll
        for (int r = 0; r < 2; ++r) {
            int base = e0[r] + b * 16;
            if (base + 16 <= e1[r]) {  // full batch
#pragma unroll
                for (int j = 0; j < 4; ++j)
                    v[r][j] = h1[(size_t)csr_src[base + 4 * j + a] * 16 + s];
            } else if (base < e1[r]) {  // masked tail
#pragma unroll
                for (int j = 0; j < 4; ++j) {
                    int idx = base + 4 * j + a;
                    int cidx = min(idx, e1[r] - 1);
                    uint2 vv = h1[(size_t)csr_src[cidx] * 16 + s];
                    bool ok = idx < e1[r];
                    v[r][j].x = ok ? vv.x : 0u;
                    v[r][j].y = ok ? vv.y : 0u;
                }
            } else {
#pragma unroll
                for (int j = 0; j < 4; ++j) v[r][j] = make_uint2(0u, 0u);
            }
        }
#pragma unroll
        for (int r = 0; r < 2; ++r)
#pragma unroll
            for (int j = 0; j < 4; ++j) {
                acc[r][0] += __builtin_amdgcn_cvt_pk_f32_fp8((int)v[r][j].x, false);
                acc[r][1] += __builtin_amdgcn_cvt_pk_f32_fp8((int)v[r][j].x, true);
                acc[r][2] += __builtin_amdgcn_cvt_pk_f32_fp8((int)v[r][j].y, false);
                acc[r][3] += __builtin_amdgcn_cvt_pk_f32_fp8((int)v[r][j].y, true);
            }
    }
#pragma unroll
    for (int r = 0; r < 2; ++r)
#pragma unroll
        for (int k = 0; k < 4; ++k) {
            v2f t;
            t[0] = __shfl_xor(acc[r][k][0], 16);
            t[1] = __shfl_xor(acc[r][k][1], 16);
            acc[r][k] += t;
            t[0] = __shfl_xor(acc[r][k][0], 32);
            t[1] = __shfl_xor(acc[r][k][1], 32);
            acc[r][k] += t;
        }
    if (a == 0) {
        float bbl[4] = {b1[s], b1[32 + s], b1[64 + s], b1[96 + s]};
        float bbh[4] = {b1[16 + s], b1[48 + s], b1[80 + s], b1[112 + s]};
#pragma unroll
        for (int r = 0; r < 2; ++r) {
            if (r0 + r < n) {
                float nd = rsqrtf((float)max(e1[r] - e0[r], 1));
                float ns = rsqrtf((float)max(deg[r0 + r], 1));
                uint w[4];
#pragma unroll
                for (int k = 0; k < 4; ++k) {
                    float fl = fmaxf(fmaf(acc[r][k][0], nd, bbl[k]), 0.f) * ns;
                    float fh = fmaxf(fmaf(acc[r][k][1], nd, bbh[k]), 0.f) * ns;
                    union { __hip_bfloat16 b; ushort u; } cl, ch;
                    cl.b = __float2bfloat16(fl);
                    ch.b = __float2bfloat16(fh);
                    w[k] = (uint)cl.u | ((uint)ch.u << 16);
                }
                x2n[(size_t)(r0 + r) * 16 + s] = make_uint4(w[0], w[1], w[2], w[3]);
            }
        }
    }
}

// ---- SpMM layer 2 + fused mean-pool: 4 rows/wave, u32 gathers (R14) -----
// h2 row = 16 u32 (64B). lane: a=lane>>4 edge sub-idx, s=lane&15 slot.
// slot s byte c <-> feat 16c+s.
__launch_bounds__(256)
__global__ void spmm2_kernel(const uint* __restrict__ h2,
                             const int* __restrict__ row_start,
                             const int* __restrict__ csr_src,
                             const float* __restrict__ b2,
                             const int* __restrict__ gids,
                             const int* __restrict__ gcnt,
                             float* __restrict__ out, int n) {
    int wv = (blockIdx.x * blockDim.x + threadIdx.x) >> 6;
    int lane = threadIdx.x & 63;
    int wave = threadIdx.x >> 6;
    int r0 = wv * 4;
    int a = lane >> 4;
    int s = lane & 15;
    int e0[4], e1[4], g[4];
    float inv[4];
#pragma unroll
    for (int r = 0; r < 4; ++r) {
        int rr = min(r0 + r, n - 1);
        e0[r] = row_start[rr];
        e1[r] = row_start[rr + 1];
        g[r] = gids[rr];
        if (r0 + r >= n) { e1[r] = e0[r]; g[r] = -1; }
        inv[r] = 1.f / (float)max(gcnt[max(g[r], 0)], 1);
    }
    float acc[4][4] = {};
    int nb = 0;
#pragma unroll
    for (int r = 0; r < 4; ++r) nb = max(nb, (e1[r] - e0[r] + 15) >> 4);
    for (int b = 0; b < nb; ++b) {
        uint u[4][4];
#pragma unroll
        for (int r = 0; r < 4; ++r) {
            int base = e0[r] + b * 16;
            if (base + 16 <= e1[r]) {  // full batch
#pragma unroll
                for (int j = 0; j < 4; ++j)
                    u[r][j] = h2[(size_t)csr_src[base + 4 * j + a] * 16 + s];
            } else if (base < e1[r]) {  // masked tail
#pragma unroll
                for (int j = 0; j < 4; ++j) {
                    int idx = base + 4 * j + a;
                    int cidx = min(idx, e1[r] - 1);
                    uint vv = h2[(size_t)csr_src[cidx] * 16 + s];
                    u[r][j] = (idx < e1[r]) ? vv : 0u;
                }
            } else {
#pragma unroll
                for (int j = 0; j < 4; ++j) u[r][j] = 0u;
            }
        }
#pragma unroll
        for (int r = 0; r < 4; ++r)
#pragma unroll
            for (int j = 0; j < 4; ++j) {
                v2f lo = __builtin_amdgcn_cvt_pk_f32_fp8((int)u[r][j], false);
                v2f hi = __builtin_amdgcn_cvt_pk_f32_fp8((int)u[r][j], true);
                acc[r][0] += lo[0]; acc[r][1] += lo[1];
                acc[r][2] += hi[0]; acc[r][3] += hi[1];
            }
    }
#pragma unroll
    for (int r = 0; r < 4; ++r)
#pragma unroll
        for (int k = 0; k < 4; ++k) {
            acc[r][k] += __shfl_xor(acc[r][k], 16);
            acc[r][k] += __shfl_xor(acc[r][k], 32);
        }
    float bb0 = b2[s], bb1 = b2[16 + s], bb2v = b2[32 + s], bb3 = b2[48 + s];
    float val[4][4];
#pragma unroll
    for (int r = 0; r < 4; ++r) {
        float nd = rsqrtf((float)max(e1[r] - e0[r], 1));
        bool vld = g[r] >= 0;
        val[r][0] = vld ? fmaxf(fmaf(acc[r][0], nd, bb0), 0.f) * inv[r] : 0.f;
        val[r][1] = vld ? fmaxf(fmaf(acc[r][1], nd, bb1), 0.f) * inv[r] : 0.f;
        val[r][2] = vld ? fmaxf(fmaf(acc[r][2], nd, bb2v), 0.f) * inv[r] : 0.f;
        val[r][3] = vld ? fmaxf(fmaf(acc[r][3], nd, bb3), 0.f) * inv[r] : 0.f;
    }
    __shared__ float sbuf[4][64];
    __shared__ int sg[4];
    bool same = (g[0] == g[1]) && (g[1] == g[2]) && (g[2] == g[3]) && (g[0] >= 0);
    int sgw;
    if (same) {
        if (a == 0) {
            sbuf[wave][s]      = val[0][0] + val[1][0] + val[2][0] + val[3][0];
            sbuf[wave][16 + s] = val[0][1] + val[1][1] + val[2][1] + val[3][1];
            sbuf[wave][32 + s] = val[0][2] + val[1][2] + val[2][2] + val[3][2];
            sbuf[wave][48 + s] = val[0][3] + val[1][3] + val[2][3] + val[3][3];
        }
        sgw = g[0];
    } else {
        if (a == 0) {
#pragma unroll
            for (int r = 0; r < 4; ++r) {
                if (g[r] >= 0) {
                    atomicAdd(&out[(size_t)g[r] * 64 + s], val[r][0]);
                    atomicAdd(&out[(size_t)g[r] * 64 + 16 + s], val[r][1]);
                    atomicAdd(&out[(size_t)g[r] * 64 + 32 + s], val[r][2]);
                    atomicAdd(&out[(size_t)g[r] * 64 + 48 + s], val[r][3]);
                }
            }
            sbuf[wave][s] = 0.f;
            sbuf[wave][16 + s] = 0.f;
            sbuf[wave][32 + s] = 0.f;
            sbuf[wave][48 + s] = 0.f;
        }
        sgw = -1;
    }
    if (lane == 0) sg[wave] = sgw;
    __syncthreads();
    if (wave == 0) {
        int g0 = sg[0], g1 = sg[1], g2 = sg[2], g3 = sg[3];
        if (g0 == g1 && g1 == g2 && g2 == g3 && g0 >= 0) {
            float ssum = sbuf[0][lane] + sbuf[1][lane] + sbuf[2][lane] + sbuf[3][lane];
            atomicAdd(&out[(size_t)g0 * 64 + lane], ssum);
        } else {
#pragma unroll
            for (int w = 0; w < 4; ++w)
                if (sg[w] >= 0)
                    atomicAdd(&out[(size_t)sg[w] * 64 + lane], sbuf[w][lane]);
        }
    }
}

extern "C" void kernel_launch(void* const* d_in, const int* in_sizes, int n_in,
                              void* d_out, int out_size, void* d_ws, size_t ws_size,
                              hipStream_t stream) {
    const float* features = (const float*)d_in[0];
    const float* W1 = (const float*)d_in[1];
    const float* b1 = (const float*)d_in[2];
    const float* W2 = (const float*)d_in[3];
    const float* b2 = (const float*)d_in[4];
    const int* src = (const int*)d_in[5];
    const int* dst = (const int*)d_in[6];
    const int* gids = (const int*)d_in[7];
    const int N = in_sizes[7];
    const int E = in_sizes[5];
    const int G = out_size / 64;  // out_size is FLOAT ELEMENTS: [G][64] f32
    float* out = (float*)d_out;
    const int P = (N + NPP - 1) >> NPP_SHIFT;

    char* ws = (char*)d_ws;
    size_t off = 0;
    auto alloc = [&](size_t bytes) -> void* {
        void* p = ws + off;
        off = (off + bytes + 255) & ~(size_t)255;
        return p;
    };
    // contiguous zero block: gcnt[G] | deg[N] | cur[P]
    int* zblock = (int*)alloc((size_t)(G + N + P) * 4);
    int* gcnt = zblock;
    int* deg = zblock + G;
    int* cur = deg + N;
    int2* ebuf_dst = (int2*)alloc((size_t)P * CAPP * 8);
    int* row_start = (int*)alloc((size_t)(N + 1) * 4);
    int* csr_src = (int*)alloc((size_t)E * 4);
    uint* h1 = (uint*)alloc((size_t)N * 128);                            // fp8 [N][128]
    __hip_bfloat16* x2n = (__hip_bfloat16*)alloc((size_t)N * 128 * 2);   // bf16, permuted
    uint* h2 = h1;  // fp8 [N][64] (64B rows); h1 dead after spmm1

    hipMemsetAsync(out, 0, (size_t)out_size * sizeof(float), stream);
    hipMemsetAsync(zblock, 0, (size_t)(G + N + P) * 4, stream);

    // --- one-pass graph build (+deg/gcnt) and CSR ---
    buildC<<<NB, 256, 0, stream>>>(src, dst, E, P, cur, ebuf_dst, deg, gids, N, G, gcnt);
    passD2<<<P, 512, 0, stream>>>(ebuf_dst, cur, row_start, csr_src, N, E, P);

    // Layer 1: h1(fp8, permuted) = (features * rsqrt(deg)) @ W1
    gemm_mfma<128, false, false, true><<<768, 256, 0, stream>>>(features, W1, deg,
                                                                (void*)h1, N);
    // SpMM 1: 2 rows/wave, uint2 gathers
    {
        int waves = (N + 1) / 2;
        int blocks = (waves * 64 + 255) / 256;
        spmm1_kernel<<<blocks, 256, 0, stream>>>((const uint2*)h1, row_start, csr_src, b1,
                                                 deg, (uint4*)x2n, N);
    }
    // Layer 2: h2(fp8, 64B rows) = x2n(permuted) @ W2  (W rows permuted to match)
    gemm_mfma<64, true, true, true><<<768, 256, 0, stream>>>(x2n, W2, nullptr,
                                                             (void*)h2, N);
    // SpMM 2 + fused mean-pool: 4 rows/wave (R14 structure)
    {
        int waves = (N + 3) / 4;
        int blocks = (waves * 64 + 255) / 256;
        spmm2_kernel<<<blocks, 256, 0, stream>>>(h2, row_start, csr_src, b2,
                                                 gids, gcnt, out, N);
    }
}

// Round 7
// 283.877 us; speedup vs baseline: 1.1226x; 1.1226x over previous
//
#include <hip/hip_runtime.h>
#include <hip/hip_bf16.h>

// ---------------------------------------------------------------------------
// GCN 2-layer forward on MI355X.
// Round 17: R16's buildC was 82us, stalled (VALU 1.1%) on 1.6M per-edge
// GLOBAL deg atomics = memory-side RMWs (~51MB extra WRITE_SIZE, atomic
// throughput wall). Fix: no per-edge global atomics. buildAC = LDS hist of
// src+dst partitions -> per-partition cursor reservation (196x2 atomics per
// block) -> scatter src(4B) + (d,s)(8B) into CAP-padded buckets (single
// edge-list read). passD3 = norm_src via LDS hist of src bucket + CSR with
// tight offsets from in-block scan of dst cursors. spmm1 (R15 uint2),
// spmm2 (R14 u32), gemms, fp8 h1/h2, fused pool all best-known.
// ---------------------------------------------------------------------------

#define NPP_SHIFT 9
#define NPP 512
#define MAXP 256
#define NB 512
#define CAPP 10240  // per-partition bucket capacity (mean 8163, sigma~90)

typedef __attribute__((ext_vector_type(8))) short frag8;
typedef __attribute__((ext_vector_type(4))) float f32x4;
typedef __attribute__((ext_vector_type(2))) float v2f;

// ---- buildAC: one-pass dual bucketing (src + dst streams) ---------------
__launch_bounds__(256)
__global__ void buildAC(const int* __restrict__ src, const int* __restrict__ dst,
                        int E, int P, int* __restrict__ cur,
                        int* __restrict__ ebuf_src, int2* __restrict__ ebuf_dst,
                        const int* __restrict__ gids, int N, int G,
                        int* __restrict__ gcnt) {
    __shared__ int hs[MAXP], hd[MAXP], bs1[MAXP], bs2[MAXP], hg[MAXP];
    int tid = threadIdx.x;
    for (int i = tid; i < MAXP; i += 256) { hs[i] = 0; hd[i] = 0; hg[i] = 0; }
    __syncthreads();
    int per_block = (E + NB - 1) / NB;
    int e0 = blockIdx.x * per_block;
    int e1 = min(e0 + per_block, E);
    for (int e = e0 + tid; e < e1; e += 256) {
        atomicAdd(&hs[src[e] >> NPP_SHIFT], 1);
        atomicAdd(&hd[dst[e] >> NPP_SHIFT], 1);
    }
    int npb = (N + NB - 1) / NB;
    int n0 = blockIdx.x * npb;
    int n1 = min(n0 + npb, N);
    for (int i = n0 + tid; i < n1; i += 256) atomicAdd(&hg[gids[i]], 1);
    __syncthreads();
    for (int p = tid; p < P; p += 256) {
        int c1 = hs[p];
        bs1[p] = c1 ? atomicAdd(&cur[p], c1) : 0;
        int c2 = hd[p];
        bs2[p] = c2 ? atomicAdd(&cur[P + p], c2) : 0;
        hs[p] = 0;
        hd[p] = 0;
    }
    for (int i = tid; i < G; i += 256)
        if (hg[i]) atomicAdd(&gcnt[i], hg[i]);
    __syncthreads();
    for (int e = e0 + tid; e < e1; e += 256) {
        int s = src[e];
        int d = dst[e];
        int p1 = s >> NPP_SHIFT;
        int p2 = d >> NPP_SHIFT;
        int l1 = atomicAdd(&hs[p1], 1);
        ebuf_src[(size_t)p1 * CAPP + bs1[p1] + l1] = s;
        int l2 = atomicAdd(&hd[p2], 1);
        ebuf_dst[(size_t)p2 * CAPP + bs2[p2] + l2] = make_int2(d, s);
    }
}

// ---- passD3: norm_src + row_start + csr build per partition -------------
__launch_bounds__(512)
__global__ void passD3(const int* __restrict__ ebuf_src, const int2* __restrict__ ebuf_dst,
                       const int* __restrict__ cur, float* __restrict__ norm_src,
                       int* __restrict__ row_start, int* __restrict__ csr_src,
                       int N, int E, int P) {
    __shared__ int hs[NPP], hd[NPP], sc[NPP];
    int tid = threadIdx.x;
    int p = blockIdx.x;
    // global CSR base for this partition = prefix sum of dst counts cur[P..P+p)
    sc[tid] = (tid < P) ? cur[P + tid] : 0;
    __syncthreads();
    for (int off = 1; off < 512; off <<= 1) {
        int t = (tid >= off) ? sc[tid - off] : 0;
        __syncthreads();
        sc[tid] += t;
        __syncthreads();
    }
    int gbase = (p > 0) ? sc[p - 1] : 0;
    __syncthreads();
    int node_lo = p << NPP_SHIFT;
    int nl = min(NPP, N - node_lo);
    hs[tid] = 0;
    hd[tid] = 0;
    __syncthreads();
    int nsrc = cur[p];
    size_t base_s = (size_t)p * CAPP;
    for (int i = tid; i < nsrc; i += 512)
        atomicAdd(&hs[ebuf_src[base_s + i] - node_lo], 1);
    int ndst = cur[P + p];
    size_t base_d = (size_t)p * CAPP;
    for (int i = tid; i < ndst; i += 512)
        atomicAdd(&hd[ebuf_dst[base_d + i].x - node_lo], 1);
    __syncthreads();
    if (tid < nl) norm_src[node_lo + tid] = rsqrtf((float)max(hs[tid], 1));
    int myh = hd[tid];
    sc[tid] = myh;
    __syncthreads();
    for (int off = 1; off < 512; off <<= 1) {
        int t = (tid >= off) ? sc[tid - off] : 0;
        __syncthreads();
        sc[tid] += t;
        __syncthreads();
    }
    int row0 = gbase + sc[tid] - myh;
    if (tid < nl) row_start[node_lo + tid] = row0;
    if (p == P - 1 && tid == 0) row_start[N] = E;
    __syncthreads();
    hd[tid] = row0;  // reuse as cursor
    __syncthreads();
    for (int i = tid; i < ndst; i += 512) {
        int2 r = ebuf_dst[base_d + i];
        int pos = atomicAdd(&hd[r.x - node_lo], 1);
        csr_src[pos] = r.y;
    }
}

// ---- MFMA GEMM: out[n x COLS] = A[n x 128] @ W[128 x COLS] --------------
// FP8OUT, COLS==128: u32 slot s, byte c <-> feature 64*(s&1) + 16*c + (s>>1)
// FP8OUT, COLS==64:  u32 slot s, byte c <-> feature 16*c + s
// PERM: LDS W row k sources w[feat(k)] to absorb the permuted A layout.
template <int COLS, bool BF16IN, bool PERM, bool FP8OUT>
__launch_bounds__(256)
__global__ void gemm_mfma(const void* __restrict__ xin, const float* __restrict__ w,
                          const float* __restrict__ norm,
                          void* __restrict__ out, int n) {
    constexpr int NT = COLS / 16;
    __shared__ short wlds[4 * NT * 64 * 8];
    const int tid = threadIdx.x;
    for (int i = tid; i < 128 * COLS / 4; i += 256) {
        int k = (i * 4) / COLS;
        int n0 = (i * 4) % COLS;
        float4 wv;
        if constexpr (PERM) {
            int ksrc = 64 * ((k >> 2) & 1) + 16 * (k & 3) + (k >> 3);
            wv = *reinterpret_cast<const float4*>(w + (size_t)ksrc * COLS + n0);
        } else {
            wv = reinterpret_cast<const float4*>(w)[i];
        }
        int c = k >> 5, q = (k >> 3) & 3, j = k & 7;
        float vals[4] = {wv.x, wv.y, wv.z, wv.w};
#pragma unroll
        for (int u = 0; u < 4; ++u) {
            int nn = n0 + u;
            int t = nn >> 4;
            int ln = (q << 4) | (nn & 15);
            union { __hip_bfloat16 b; short s; } cv;
            cv.b = __float2bfloat16(vals[u]);
            wlds[(((c * NT + t) << 6) | ln) * 8 + j] = cv.s;
        }
    }
    __syncthreads();

    const int lane = tid & 63;
    const int wid = tid >> 6;
    const int m = lane & 15;
    const int q = lane >> 4;
    const int ntiles = (n + 15) >> 4;
    const frag8* wfr = reinterpret_cast<const frag8*>(wlds);

    for (int wt = blockIdx.x * 4 + wid; wt < ntiles; wt += gridDim.x * 4) {
        const int row = (wt << 4) + m;
        frag8 af[4];
        if (row < n) {
            if constexpr (BF16IN) {
                const frag8* xp = reinterpret_cast<const frag8*>(
                    (const __hip_bfloat16*)xin + (size_t)row * 128);
#pragma unroll
                for (int c = 0; c < 4; ++c) af[c] = xp[c * 4 + q];
            } else {
                const float* xp = (const float*)xin + (size_t)row * 128;
                float nm = norm[row];
#pragma unroll
                for (int c = 0; c < 4; ++c) {
                    int base = c * 32 + q * 8;
                    float4 v0 = *reinterpret_cast<const float4*>(xp + base);
                    float4 v1 = *reinterpret_cast<const float4*>(xp + base + 4);
                    union { frag8 f; short s[8]; } a;
                    union { __hip_bfloat16 b; short s; } cv;
                    cv.b = __float2bfloat16(v0.x * nm); a.s[0] = cv.s;
                    cv.b = __float2bfloat16(v0.y * nm); a.s[1] = cv.s;
                    cv.b = __float2bfloat16(v0.z * nm); a.s[2] = cv.s;
                    cv.b = __float2bfloat16(v0.w * nm); a.s[3] = cv.s;
                    cv.b = __float2bfloat16(v1.x * nm); a.s[4] = cv.s;
                    cv.b = __float2bfloat16(v1.y * nm); a.s[5] = cv.s;
                    cv.b = __float2bfloat16(v1.z * nm); a.s[6] = cv.s;
                    cv.b = __float2bfloat16(v1.w * nm); a.s[7] = cv.s;
                    af[c] = a.f;
                }
            }
        } else {
#pragma unroll
            for (int c = 0; c < 4; ++c) af[c] = frag8{0, 0, 0, 0, 0, 0, 0, 0};
        }
        f32x4 acc[NT] = {};
#pragma unroll
        for (int c = 0; c < 4; ++c)
#pragma unroll
            for (int t = 0; t < NT; ++t)
                acc[t] = __builtin_amdgcn_mfma_f32_16x16x32_bf16(
                    af[c], wfr[(c * NT + t) * 64 + lane], acc[t], 0, 0, 0);
#pragma unroll
        for (int r = 0; r < 4; ++r) {
            int grow = (wt << 4) + q * 4 + r;
            if (grow < n) {
                if constexpr (FP8OUT && COLS == 128) {
                    uint w0 = 0, w1 = 0;
                    w0 = (uint)__builtin_amdgcn_cvt_pk_fp8_f32(acc[0][r], acc[1][r], (int)w0, false);
                    w0 = (uint)__builtin_amdgcn_cvt_pk_fp8_f32(acc[2][r], acc[3][r], (int)w0, true);
                    w1 = (uint)__builtin_amdgcn_cvt_pk_fp8_f32(acc[4][r], acc[5][r], (int)w1, false);
                    w1 = (uint)__builtin_amdgcn_cvt_pk_fp8_f32(acc[6][r], acc[7][r], (int)w1, true);
                    reinterpret_cast<uint2*>(out)[(size_t)grow * 16 + m] = make_uint2(w0, w1);
                } else if constexpr (FP8OUT) {
                    uint w0 = 0;
                    w0 = (uint)__builtin_amdgcn_cvt_pk_fp8_f32(acc[0][r], acc[1][r], (int)w0, false);
                    w0 = (uint)__builtin_amdgcn_cvt_pk_fp8_f32(acc[2][r], acc[3][r], (int)w0, true);
                    reinterpret_cast<uint*>(out)[(size_t)grow * 16 + m] = w0;
                } else {
                    __hip_bfloat16* ob = reinterpret_cast<__hip_bfloat16*>(out);
#pragma unroll
                    for (int t = 0; t < NT; ++t)
                        ob[(size_t)grow * COLS + t * 16 + m] = __float2bfloat16(acc[t][r]);
                }
            }
        }
    }
}

// ---- SpMM layer 1: 2 dst rows/wave, uint2 gathers (4 edges/instr) -------
__launch_bounds__(256)
__global__ void spmm1_kernel(const uint2* __restrict__ h1,
                             const int* __restrict__ row_start,
                             const int* __restrict__ csr_src,
                             const float* __restrict__ b1,
                             const float* __restrict__ norm_src,
                             uint4* __restrict__ x2n, int n) {
    int wv = (blockIdx.x * blockDim.x + threadIdx.x) >> 6;
    int lane = threadIdx.x & 63;
    int r0 = wv * 2;
    if (r0 >= n) return;
    int a = lane >> 4;
    int s = lane & 15;
    int e0[2], e1[2];
#pragma unroll
    for (int r = 0; r < 2; ++r) {
        int rr = min(r0 + r, n - 1);
        e0[r] = row_start[rr];
        e1[r] = row_start[rr + 1];
        if (r0 + r >= n) e1[r] = e0[r];
    }
    v2f acc[2][4] = {};
    int nb = max((e1[0] - e0[0] + 15) >> 4, (e1[1] - e0[1] + 15) >> 4);
    for (int b = 0; b < nb; ++b) {
        uint2 v[2][4];
#pragma unroll
        for (int r = 0; r < 2; ++r) {
            int base = e0[r] + b * 16;
            if (base + 16 <= e1[r]) {  // full batch
#pragma unroll
                for (int j = 0; j < 4; ++j)
                    v[r][j] = h1[(size_t)csr_src[base + 4 * j + a] * 16 + s];
            } else if (base < e1[r]) {  // masked tail
#pragma unroll
                for (int j = 0; j < 4; ++j) {
                    int idx = base + 4 * j + a;
                    int cidx = min(idx, e1[r] - 1);
                    uint2 vv = h1[(size_t)csr_src[cidx] * 16 + s];
                    bool ok = idx < e1[r];
                    v[r][j].x = ok ? vv.x : 0u;
                    v[r][j].y = ok ? vv.y : 0u;
                }
            } else {
#pragma unroll
                for (int j = 0; j < 4; ++j) v[r][j] = make_uint2(0u, 0u);
            }
        }
#pragma unroll
        for (int r = 0; r < 2; ++r)
#pragma unroll
            for (int j = 0; j < 4; ++j) {
                acc[r][0] += __builtin_amdgcn_cvt_pk_f32_fp8((int)v[r][j].x, false);
                acc[r][1] += __builtin_amdgcn_cvt_pk_f32_fp8((int)v[r][j].x, true);
                acc[r][2] += __builtin_amdgcn_cvt_pk_f32_fp8((int)v[r][j].y, false);
                acc[r][3] += __builtin_amdgcn_cvt_pk_f32_fp8((int)v[r][j].y, true);
            }
    }
#pragma unroll
    for (int r = 0; r < 2; ++r)
#pragma unroll
        for (int k = 0; k < 4; ++k) {
            v2f t;
            t[0] = __shfl_xor(acc[r][k][0], 16);
            t[1] = __shfl_xor(acc[r][k][1], 16);
            acc[r][k] += t;
            t[0] = __shfl_xor(acc[r][k][0], 32);
            t[1] = __shfl_xor(acc[r][k][1], 32);
            acc[r][k] += t;
        }
    if (a == 0) {
        float bbl[4] = {b1[s], b1[32 + s], b1[64 + s], b1[96 + s]};
        float bbh[4] = {b1[16 + s], b1[48 + s], b1[80 + s], b1[112 + s]};
#pragma unroll
        for (int r = 0; r < 2; ++r) {
            if (r0 + r < n) {
                float nd = rsqrtf((float)max(e1[r] - e0[r], 1));
                float ns = norm_src[r0 + r];
                uint w[4];
#pragma unroll
                for (int k = 0; k < 4; ++k) {
                    float fl = fmaxf(fmaf(acc[r][k][0], nd, bbl[k]), 0.f) * ns;
                    float fh = fmaxf(fmaf(acc[r][k][1], nd, bbh[k]), 0.f) * ns;
                    union { __hip_bfloat16 b; ushort u; } cl, ch;
                    cl.b = __float2bfloat16(fl);
                    ch.b = __float2bfloat16(fh);
                    w[k] = (uint)cl.u | ((uint)ch.u << 16);
                }
                x2n[(size_t)(r0 + r) * 16 + s] = make_uint4(w[0], w[1], w[2], w[3]);
            }
        }
    }
}

// ---- SpMM layer 2 + fused mean-pool: 4 rows/wave, u32 gathers (R14) -----
__launch_bounds__(256)
__global__ void spmm2_kernel(const uint* __restrict__ h2,
                             const int* __restrict__ row_start,
                             const int* __restrict__ csr_src,
                             const float* __restrict__ b2,
                             const int* __restrict__ gids,
                             const int* __restrict__ gcnt,
                             float* __restrict__ out, int n) {
    int wv = (blockIdx.x * blockDim.x + threadIdx.x) >> 6;
    int lane = threadIdx.x & 63;
    int wave = threadIdx.x >> 6;
    int r0 = wv * 4;
    int a = lane >> 4;
    int s = lane & 15;
    int e0[4], e1[4], g[4];
    float inv[4];
#pragma unroll
    for (int r = 0; r < 4; ++r) {
        int rr = min(r0 + r, n - 1);
        e0[r] = row_start[rr];
        e1[r] = row_start[rr + 1];
        g[r] = gids[rr];
        if (r0 + r >= n) { e1[r] = e0[r]; g[r] = -1; }
        inv[r] = 1.f / (float)max(gcnt[max(g[r], 0)], 1);
    }
    float acc[4][4] = {};
    int nb = 0;
#pragma unroll
    for (int r = 0; r < 4; ++r) nb = max(nb, (e1[r] - e0[r] + 15) >> 4);
    for (int b = 0; b < nb; ++b) {
        uint u[4][4];
#pragma unroll
        for (int r = 0; r < 4; ++r) {
            int base = e0[r] + b * 16;
            if (base + 16 <= e1[r]) {  // full batch
#pragma unroll
                for (int j = 0; j < 4; ++j)
                    u[r][j] = h2[(size_t)csr_src[base + 4 * j + a] * 16 + s];
            } else if (base < e1[r]) {  // masked tail
#pragma unroll
                for (int j = 0; j < 4; ++j) {
                    int idx = base + 4 * j + a;
                    int cidx = min(idx, e1[r] - 1);
                    uint vv = h2[(size_t)csr_src[cidx] * 16 + s];
                    u[r][j] = (idx < e1[r]) ? vv : 0u;
                }
            } else {
#pragma unroll
                for (int j = 0; j < 4; ++j) u[r][j] = 0u;
            }
        }
#pragma unroll
        for (int r = 0; r < 4; ++r)
#pragma unroll
            for (int j = 0; j < 4; ++j) {
                v2f lo = __builtin_amdgcn_cvt_pk_f32_fp8((int)u[r][j], false);
                v2f hi = __builtin_amdgcn_cvt_pk_f32_fp8((int)u[r][j], true);
                acc[r][0] += lo[0]; acc[r][1] += lo[1];
                acc[r][2] += hi[0]; acc[r][3] += hi[1];
            }
    }
#pragma unroll
    for (int r = 0; r < 4; ++r)
#pragma unroll
        for (int k = 0; k < 4; ++k) {
            acc[r][k] += __shfl_xor(acc[r][k], 16);
            acc[r][k] += __shfl_xor(acc[r][k], 32);
        }
    float bb0 = b2[s], bb1 = b2[16 + s], bb2v = b2[32 + s], bb3 = b2[48 + s];
    float val[4][4];
#pragma unroll
    for (int r = 0; r < 4; ++r) {
        float nd = rsqrtf((float)max(e1[r] - e0[r], 1));
        bool vld = g[r] >= 0;
        val[r][0] = vld ? fmaxf(fmaf(acc[r][0], nd, bb0), 0.f) * inv[r] : 0.f;
        val[r][1] = vld ? fmaxf(fmaf(acc[r][1], nd, bb1), 0.f) * inv[r] : 0.f;
        val[r][2] = vld ? fmaxf(fmaf(acc[r][2], nd, bb2v), 0.f) * inv[r] : 0.f;
        val[r][3] = vld ? fmaxf(fmaf(acc[r][3], nd, bb3), 0.f) * inv[r] : 0.f;
    }
    __shared__ float sbuf[4][64];
    __shared__ int sg[4];
    bool same = (g[0] == g[1]) && (g[1] == g[2]) && (g[2] == g[3]) && (g[0] >= 0);
    int sgw;
    if (same) {
        if (a == 0) {
            sbuf[wave][s]      = val[0][0] + val[1][0] + val[2][0] + val[3][0];
            sbuf[wave][16 + s] = val[0][1] + val[1][1] + val[2][1] + val[3][1];
            sbuf[wave][32 + s] = val[0][2] + val[1][2] + val[2][2] + val[3][2];
            sbuf[wave][48 + s] = val[0][3] + val[1][3] + val[2][3] + val[3][3];
        }
        sgw = g[0];
    } else {
        if (a == 0) {
#pragma unroll
            for (int r = 0; r < 4; ++r) {
                if (g[r] >= 0) {
                    atomicAdd(&out[(size_t)g[r] * 64 + s], val[r][0]);
                    atomicAdd(&out[(size_t)g[r] * 64 + 16 + s], val[r][1]);
                    atomicAdd(&out[(size_t)g[r] * 64 + 32 + s], val[r][2]);
                    atomicAdd(&out[(size_t)g[r] * 64 + 48 + s], val[r][3]);
                }
            }
            sbuf[wave][s] = 0.f;
            sbuf[wave][16 + s] = 0.f;
            sbuf[wave][32 + s] = 0.f;
            sbuf[wave][48 + s] = 0.f;
        }
        sgw = -1;
    }
    if (lane == 0) sg[wave] = sgw;
    __syncthreads();
    if (wave == 0) {
        int g0 = sg[0], g1 = sg[1], g2 = sg[2], g3 = sg[3];
        if (g0 == g1 && g1 == g2 && g2 == g3 && g0 >= 0) {
            float ssum = sbuf[0][lane] + sbuf[1][lane] + sbuf[2][lane] + sbuf[3][lane];
            atomicAdd(&out[(size_t)g0 * 64 + lane], ssum);
        } else {
#pragma unroll
            for (int w = 0; w < 4; ++w)
                if (sg[w] >= 0)
                    atomicAdd(&out[(size_t)sg[w] * 64 + lane], sbuf[w][lane]);
        }
    }
}

extern "C" void kernel_launch(void* const* d_in, const int* in_sizes, int n_in,
                              void* d_out, int out_size, void* d_ws, size_t ws_size,
                              hipStream_t stream) {
    const float* features = (const float*)d_in[0];
    const float* W1 = (const float*)d_in[1];
    const float* b1 = (const float*)d_in[2];
    const float* W2 = (const float*)d_in[3];
    const float* b2 = (const float*)d_in[4];
    const int* src = (const int*)d_in[5];
    const int* dst = (const int*)d_in[6];
    const int* gids = (const int*)d_in[7];
    const int N = in_sizes[7];
    const int E = in_sizes[5];
    const int G = out_size / 64;  // out_size is FLOAT ELEMENTS: [G][64] f32
    float* out = (float*)d_out;
    const int P = (N + NPP - 1) >> NPP_SHIFT;

    char* ws = (char*)d_ws;
    size_t off = 0;
    auto alloc = [&](size_t bytes) -> void* {
        void* p = ws + off;
        off = (off + bytes + 255) & ~(size_t)255;
        return p;
    };
    // contiguous zero block: gcnt[G] | cur[2P]
    int* zblock = (int*)alloc((size_t)(G + 2 * P) * 4);
    int* gcnt = zblock;
    int* cur = zblock + G;
    int* ebuf_src = (int*)alloc((size_t)P * CAPP * 4);
    int2* ebuf_dst = (int2*)alloc((size_t)P * CAPP * 8);
    float* norm_src = (float*)alloc((size_t)N * 4);
    int* row_start = (int*)alloc((size_t)(N + 1) * 4);
    int* csr_src = (int*)alloc((size_t)E * 4);
    uint* h1 = (uint*)alloc((size_t)N * 128);                            // fp8 [N][128]
    __hip_bfloat16* x2n = (__hip_bfloat16*)alloc((size_t)N * 128 * 2);   // bf16, permuted
    uint* h2 = h1;  // fp8 [N][64] (64B rows); h1 dead after spmm1

    hipMemsetAsync(out, 0, (size_t)out_size * sizeof(float), stream);
    hipMemsetAsync(zblock, 0, (size_t)(G + 2 * P) * 4, stream);

    // --- one-pass dual bucketing + CSR/norm build ---
    buildAC<<<NB, 256, 0, stream>>>(src, dst, E, P, cur, ebuf_src, ebuf_dst,
                                    gids, N, G, gcnt);
    passD3<<<P, 512, 0, stream>>>(ebuf_src, ebuf_dst, cur, norm_src, row_start,
                                  csr_src, N, E, P);

    // Layer 1: h1(fp8, permuted) = (features * norm_src) @ W1
    gemm_mfma<128, false, false, true><<<768, 256, 0, stream>>>(features, W1, norm_src,
                                                                (void*)h1, N);
    // SpMM 1: 2 rows/wave, uint2 gathers
    {
        int waves = (N + 1) / 2;
        int blocks = (waves * 64 + 255) / 256;
        spmm1_kernel<<<blocks, 256, 0, stream>>>((const uint2*)h1, row_start, csr_src, b1,
                                                 norm_src, (uint4*)x2n, N);
    }
    // Layer 2: h2(fp8, 64B rows) = x2n(permuted) @ W2  (W rows permuted to match)
    gemm_mfma<64, true, true, true><<<768, 256, 0, stream>>>(x2n, W2, nullptr,
                                                             (void*)h2, N);
    // SpMM 2 + fused mean-pool: 4 rows/wave (R14 structure)
    {
        int waves = (N + 3) / 4;
        int blocks = (waves * 64 + 255) / 256;
        spmm2_kernel<<<blocks, 256, 0, stream>>>(h2, row_start, csr_src, b2,
                                                 gids, gcnt, out, N);
    }
}